// Round 8
// baseline (929.855 us; speedup 1.0000x reference)
//
#include <hip/hip_runtime.h>
#include <float.h>

#define NLVL 12
#define NB   16
#define NGRP 16

// meta: [0..16) cf | [16..32) cb | [32..48) co | [48..64) curf | [64..80) curb |
//       [80..96) curo | [96..109) base_f | [128..141) base_b | [160..177) base_o
// packed entry: id(18b) | fl(4b)<<18 | bl(4b)<<22   (N=200k < 2^18)
// bar layout (ints, zeroed each call): fwd: [g*16] g<16 group ctrs, [256] root, [260] epoch
//                                      bwd: +512 same layout

struct Params {
    const int *nt, *ninv, *src, *dst, *fl, *bl, *batch;
    const float *We, *be, *Wf, *bf, *Wb, *bb;
    float *h, *hN, *out;
    int *rowptr, *cursor, *col, *nb_f, *nb_b, *onodes, *bsums, *meta, *plarr, *bar;
    int N, E, M, outN, grpsz;
};

// ---- two-level epoch barrier: leader-only fences, relaxed arrivals/polls ----
// (r5/r6 post-mortem: per-thread threadfence + acquire-polls were the poison;
//  this is the fixed protocol. Monotone counters -> no reset races.)
__device__ __forceinline__ void gbar(int* bar, int ep, int grpsz) {
    __syncthreads();
    if (threadIdx.x == 0) {
        __builtin_amdgcn_fence(__ATOMIC_RELEASE, "agent");   // one wbl2 per block
        int g = blockIdx.x & (NGRP - 1);
        int pos = __hip_atomic_fetch_add(&bar[g * 16], 1, __ATOMIC_RELAXED, __HIP_MEMORY_SCOPE_AGENT);
        if (pos == ep * grpsz - 1) {
            int r = __hip_atomic_fetch_add(&bar[256], 1, __ATOMIC_RELAXED, __HIP_MEMORY_SCOPE_AGENT);
            if (r == ep * NGRP - 1)
                __hip_atomic_store(&bar[260], ep, __ATOMIC_RELAXED, __HIP_MEMORY_SCOPE_AGENT);
        }
        while (__hip_atomic_load(&bar[260], __ATOMIC_RELAXED, __HIP_MEMORY_SCOPE_AGENT) < ep)
            __builtin_amdgcn_s_sleep(1);
        __builtin_amdgcn_fence(__ATOMIC_ACQUIRE, "agent");   // one inv per block
    }
    __syncthreads();
}

// ---------------- degrees + histograms + packed levels + encoder ----------------
__global__ void k_deg_hist(Params p) {
    __shared__ int hf[NLVL], hb[NLVL], ho[NB];
    if (threadIdx.x < NLVL) { hf[threadIdx.x] = 0; hb[threadIdx.x] = 0; }
    if (threadIdx.x < NB) ho[threadIdx.x] = 0;
    __syncthreads();
    int g = blockIdx.x * blockDim.x + threadIdx.x, gs = gridDim.x * blockDim.x;
    for (int e = g; e < p.E; e += gs) {
        atomicAdd(&p.rowptr[p.dst[e]], 1);
        atomicAdd(&p.rowptr[p.N + p.src[e]], 1);
    }
    for (int i = g; i < p.N; i += gs) {
        int f = p.fl[i], b = p.bl[i];
        p.plarr[i] = f | (b << 4);
        atomicAdd(&hf[f], 1);
        atomicAdd(&hb[b], 1);
        if (p.nt[i] == 1) atomicAdd(&ho[p.batch[i]], 1);
    }
    // encoder (independent of the atomics above; overlaps their latency)
    for (int t = g; t < p.N * 16; t += gs) {
        int v = t >> 4;
        int j = (t & 15) * 4;
        float a = (float)p.nt[v], c = (float)p.ninv[v];
        float4 w0 = *(const float4*)(p.We + j);
        float4 w1 = *(const float4*)(p.We + 64 + j);
        float4 b  = *(const float4*)(p.be + j);
        float4 r;
        r.x = fmaf(a, w0.x, fmaf(c, w1.x, b.x));
        r.y = fmaf(a, w0.y, fmaf(c, w1.y, b.y));
        r.z = fmaf(a, w0.z, fmaf(c, w1.z, b.z));
        r.w = fmaf(a, w0.w, fmaf(c, w1.w, b.w));
        *(float4*)(p.h + (size_t)v * 64 + j) = r;
    }
    __syncthreads();
    if (threadIdx.x < NLVL) { atomicAdd(&p.meta[threadIdx.x], hf[threadIdx.x]); atomicAdd(&p.meta[16 + threadIdx.x], hb[threadIdx.x]); }
    if (threadIdx.x < NB) atomicAdd(&p.meta[32 + threadIdx.x], ho[threadIdx.x]);
}

// ---------------- 3-kernel exclusive scan over M = 2N ----------------
__global__ void k_scan1(int* __restrict__ data, int M, int* __restrict__ bsums) {
    __shared__ int s[512];
    int t = threadIdx.x;
    int g = blockIdx.x * 512 + t;
    int v = (g < M) ? data[g] : 0;
    s[t] = v;
    __syncthreads();
    for (int off = 1; off < 512; off <<= 1) {
        int add = (t >= off) ? s[t - off] : 0;
        __syncthreads();
        s[t] += add;
        __syncthreads();
    }
    if (g < M) data[g] = s[t] - v;
    if (t == 511) bsums[blockIdx.x] = s[511];
}

__global__ void k_scan_top(int* __restrict__ bsums, int nblk, int* __restrict__ meta,
                           float* __restrict__ out, int outN) {
    __shared__ int s[1024];
    int t = threadIdx.x;
    if (t == 0) { int a = 0; for (int l = 0; l < NLVL; l++) { meta[96 + l] = a; meta[48 + l] = a; a += meta[l]; } meta[96 + NLVL] = a; }
    if (t == 1) { int a = 0; for (int l = 0; l < NLVL; l++) { meta[128 + l] = a; meta[64 + l] = a; a += meta[16 + l]; } meta[128 + NLVL] = a; }
    if (t == 2) { int a = 0; for (int b = 0; b < NB; b++) { meta[160 + b] = a; meta[80 + b] = a; a += meta[32 + b]; } meta[160 + NB] = a; }
    for (int i = t; i < outN; i += 1024)
        out[i] = ((i & 127) < 64) ? -FLT_MAX : 0.0f;   // max-pool init == finfo.min
    int v = (t < nblk) ? bsums[t] : 0;
    s[t] = v;
    __syncthreads();
    for (int off = 1; off < 1024; off <<= 1) {
        int add = (t >= off) ? s[t - off] : 0;
        __syncthreads();
        s[t] += add;
        __syncthreads();
    }
    if (t < nblk) bsums[t] = s[t] - v;
}

__global__ void k_scan_add(int* __restrict__ rowptr, int* __restrict__ cursor, int M, int total,
                           const int* __restrict__ bsums) {
    int g = blockIdx.x * blockDim.x + threadIdx.x;
    if (g >= M) return;
    int r = rowptr[g] + bsums[g >> 9];
    rowptr[g] = r;
    cursor[g] = r;
    if (g == 0) rowptr[M] = total;
}

// ---------------- packed CSR fill + packed node scatter ----------------
__global__ void k_fill(Params p) {
    __shared__ int hf[NLVL], hb[NLVL], ho[NB], basef[NLVL], baseb[NLVL], baseo[NB];
    int g = blockIdx.x * blockDim.x + threadIdx.x, gs = gridDim.x * blockDim.x;
    int tid = threadIdx.x;
    int N = p.N;

    for (int e = g; e < p.E; e += gs) {
        int s = p.src[e], d = p.dst[e];
        p.col[atomicAdd(&p.cursor[d], 1)] = s | (p.plarr[s] << 18);      // in-edge: other = src
        p.col[atomicAdd(&p.cursor[N + s], 1)] = d | (p.plarr[d] << 18);  // out-edge: other = dst
    }

    for (int i0 = blockIdx.x * blockDim.x; i0 < N; i0 += gs) {
        int i = i0 + tid;
        bool valid = (i < N);
        if (tid < NLVL) { hf[tid] = 0; hb[tid] = 0; }
        if (tid < NB) ho[tid] = 0;
        __syncthreads();
        int lf = 0, lb = 0, ob = -1;
        if (valid) {
            lf = p.fl[i]; lb = p.bl[i];
            atomicAdd(&hf[lf], 1);
            atomicAdd(&hb[lb], 1);
            if (p.nt[i] == 1) { ob = p.batch[i]; atomicAdd(&ho[ob], 1); }
        }
        __syncthreads();
        if (tid < NLVL) {
            basef[tid] = atomicAdd(&p.meta[48 + tid], hf[tid]);
            baseb[tid] = atomicAdd(&p.meta[64 + tid], hb[tid]);
            hf[tid] = 0; hb[tid] = 0;
        }
        if (tid < NB) {
            baseo[tid] = atomicAdd(&p.meta[80 + tid], ho[tid]);
            ho[tid] = 0;
        }
        __syncthreads();
        if (valid) {
            int pk = i | ((lf | (lb << 4)) << 18);
            p.nb_f[basef[lf] + atomicAdd(&hf[lf], 1)] = pk;
            p.nb_b[baseb[lb] + atomicAdd(&hb[lb], 1)] = pk;
            if (ob >= 0) p.onodes[baseo[ob] + atomicAdd(&ho[ob], 1)] = pk;
        }
        __syncthreads();
    }
}

// ---------------- one level phase (parity verified r4/r5/r7) ----------------
__device__ __forceinline__ void sweep_phase(const Params& p, const float* Ws, float bv,
                                            int lvl, int dir, int wid, int nw, int lane) {
    const int* nb = dir ? p.nb_b : p.nb_f;
    const int* rp = p.rowptr + (dir ? p.N : 0);
    int start = p.meta[(dir ? 128 : 96) + lvl];
    int cnt   = p.meta[(dir ? 128 : 96) + lvl + 1] - start;
    const int q = lane >> 4, fb = (lane & 15) * 4;
    int c0 = (int)((long long)cnt * wid / nw);
    int c1 = (int)((long long)cnt * (wid + 1) / nw);
    for (int g0 = c0; g0 < c1; g0 += 64) {
        int take = c1 - g0; if (take > 64) take = 64;
        int el = 0, rpvl = 0, rpel = 0;
        if (lane < take) {
            int e = nb[start + g0 + lane];      // coalesced id preload
            el = e;
            int v = e & 0x3FFFF;
            rpvl = rp[v]; rpel = rp[v + 1];
        }
        for (int j = 0; j < take; j++) {
            int e   = __shfl(el, j, 64);
            int rpv = __shfl(rpvl, j, 64);
            int rpe = __shfl(rpel, j, 64);
            int v   = e & 0x3FFFF;
            int flv = (e >> 18) & 15;
            float4 acc = make_float4(0.f, 0.f, 0.f, 0.f);
            for (int cb = rpv + q; cb < rpe; cb += 4) {
                int cu = p.col[cb];
                int u = cu & 0x3FFFF;
                int flu = (cu >> 18) & 15, blu = (cu >> 22) & 15;
                bool useN = (dir == 0) ? (flu > 0 && flu < lvl)
                                       : ((flu > 0) != (blu > 0 && blu < lvl));
                const float* sb = useN ? p.hN : p.h;
                const float4 x = *(const float4*)(sb + (size_t)u * 64 + fb);
                acc.x += x.x; acc.y += x.y; acc.z += x.z; acc.w += x.w;
            }
            acc.x += __shfl_xor(acc.x, 16, 64); acc.y += __shfl_xor(acc.y, 16, 64);
            acc.z += __shfl_xor(acc.z, 16, 64); acc.w += __shfl_xor(acc.w, 16, 64);
            acc.x += __shfl_xor(acc.x, 32, 64); acc.y += __shfl_xor(acc.y, 32, 64);
            acc.z += __shfl_xor(acc.z, 32, 64); acc.w += __shfl_xor(acc.w, 32, 64);
            float o = bv * (float)(rpe - rpv);
            #pragma unroll
            for (int k = 0; k < 16; k++) {
                float ax = __shfl(acc.x, k, 64);
                float ay = __shfl(acc.y, k, 64);
                float az = __shfl(acc.z, k, 64);
                float aw = __shfl(acc.w, k, 64);
                o = fmaf(ax, Ws[(4 * k + 0) * 64 + lane], o);
                o = fmaf(ay, Ws[(4 * k + 1) * 64 + lane], o);
                o = fmaf(az, Ws[(4 * k + 2) * 64 + lane], o);
                o = fmaf(aw, Ws[(4 * k + 3) * 64 + lane], o);
            }
            float* db = (dir == 0) ? p.hN : ((flv > 0) ? p.h : p.hN);
            db[(size_t)v * 64 + lane] = o;
        }
    }
}

// ---------------- forward sweep: 11 phases, 10 in-kernel barriers ----------------
__global__ __launch_bounds__(256, 2) void k_sweep_f(Params p) {
    __shared__ float Ws[4096];
    for (int i = threadIdx.x; i < 4096; i += 256) Ws[i] = p.Wf[i];
    __syncthreads();
    const int lane = threadIdx.x & 63;
    const int wid = (blockIdx.x * 256 + threadIdx.x) >> 6;
    const int nw  = (gridDim.x * 256) >> 6;
    float bv = p.bf[lane];
    for (int l = 1; l < NLVL; l++) {
        sweep_phase(p, Ws, bv, l, 0, wid, nw, lane);
        if (l < NLVL - 1) gbar(p.bar, l, p.grpsz);   // kernel boundary covers the last
    }
}

// ---------------- backward sweep + readout: 11 phases, 11 barriers ----------------
__device__ inline void atomicMaxF(float* addr, float val) {
    int* ai = (int*)addr;
    int old = *ai;
    while (__int_as_float(old) < val) {
        int assumed = old;
        old = atomicCAS(ai, assumed, __float_as_int(val));
        if (old == assumed) break;
    }
}

__global__ __launch_bounds__(256, 2) void k_sweep_b(Params p) {
    __shared__ float Ws[4096];
    for (int i = threadIdx.x; i < 4096; i += 256) Ws[i] = p.Wb[i];
    __syncthreads();
    const int lane = threadIdx.x & 63;
    const int wid = (blockIdx.x * 256 + threadIdx.x) >> 6;
    const int nw  = (gridDim.x * 256) >> 6;
    float bv = p.bb[lane];
    for (int l = 1; l < NLVL; l++) {
        sweep_phase(p, Ws, bv, l, 1, wid, nw, lane);
        gbar(p.bar + 512, l, p.grpsz);               // last barrier guards readout
    }
    // readout
    const int S = nw / NB;
    int b = wid / S, sl = wid % S;
    if (b < NB) {
        int a0 = p.meta[160 + b], a1 = p.meta[161 + b];
        int cnt = a1 - a0;
        if (cnt > 0) {
            int lo = a0 + (int)(((long long)cnt * sl) / S);
            int hi = a0 + (int)(((long long)cnt * (sl + 1)) / S);
            if (hi > lo) {
                float mx = -FLT_MAX, sm = 0.f;
                for (int k = lo; k < hi; k += 64) {
                    int take = hi - k; if (take > 64) take = 64;
                    int el = (lane < take) ? p.onodes[k + lane] : 0;
                    for (int j = 0; j < take; j++) {
                        int e = __shfl(el, j, 64);
                        int v = e & 0x3FFFF;
                        int flv = (e >> 18) & 15, blv = (e >> 22) & 15;
                        const float* sb = ((flv > 0) != (blv > 0)) ? p.hN : p.h;
                        float x = sb[(size_t)v * 64 + lane];
                        mx = fmaxf(mx, x);
                        sm += x;
                    }
                }
                atomicMaxF(&p.out[b * 128 + lane], mx);
                atomicAdd(&p.out[b * 128 + 64 + lane], sm);
            }
        }
    }
}

extern "C" void kernel_launch(void* const* d_in, const int* in_sizes, int n_in,
                              void* d_out, int out_size, void* d_ws, size_t ws_size,
                              hipStream_t stream) {
    int N = in_sizes[0];
    int E = in_sizes[2] / 2;
    int M = 2 * N;

    Params p;
    p.nt    = (const int*)d_in[0];
    p.ninv  = (const int*)d_in[1];
    p.src   = (const int*)d_in[2];
    p.dst   = (const int*)d_in[2] + E;
    p.fl    = (const int*)d_in[3];
    p.bl    = (const int*)d_in[4];
    p.batch = (const int*)d_in[5];
    p.We    = (const float*)d_in[6];
    p.be    = (const float*)d_in[7];
    p.Wf    = (const float*)d_in[8];
    p.bf    = (const float*)d_in[9];
    p.Wb    = (const float*)d_in[10];
    p.bb    = (const float*)d_in[11];
    p.out   = (float*)d_out;
    p.N = N; p.E = E; p.M = M; p.outN = out_size;

    char* ws = (char*)d_ws;
    size_t off = 0;
    auto alloc = [&](size_t bytes) -> char* {
        char* q = ws + off;
        off = (off + bytes + 255) & ~(size_t)255;
        return q;
    };
    // rowptr + meta + bar adjacent -> one memset zeroes all three
    p.rowptr = (int*)  alloc((size_t)(M + 1) * sizeof(int));
    p.meta   = (int*)  alloc(256 * sizeof(int));
    p.bar    = (int*)  alloc(1024 * sizeof(int));
    size_t zbytes = (size_t)((char*)(p.bar + 1024) - (char*)p.rowptr);
    p.h      = (float*)alloc((size_t)N * 64 * sizeof(float));
    p.hN     = (float*)alloc((size_t)N * 64 * sizeof(float));
    p.cursor = (int*)  alloc((size_t)M * sizeof(int));
    p.col    = (int*)  alloc((size_t)2 * E * sizeof(int));
    p.nb_f   = (int*)  alloc((size_t)N * sizeof(int));
    p.nb_b   = (int*)  alloc((size_t)N * sizeof(int));
    p.onodes = (int*)  alloc((size_t)N * sizeof(int));
    p.plarr  = (int*)  alloc((size_t)N * sizeof(int));
    p.bsums  = (int*)  alloc(1024 * sizeof(int));

    // cooperative grid: 512 blocks (2/CU) if resources allow, multiple of NGRP
    int occf = 0, occb = 0;
    hipOccupancyMaxActiveBlocksPerMultiprocessor(&occf, k_sweep_f, 256, 0);
    hipOccupancyMaxActiveBlocksPerMultiprocessor(&occb, k_sweep_b, 256, 0);
    int occ = occf < occb ? occf : occb;
    if (occ < 1) occ = 1;
    int G = occ * 256;
    if (G > 512) G = 512;
    G &= ~(NGRP - 1);
    if (G < NGRP) G = NGRP;
    p.grpsz = G / NGRP;

    int nscan = (M + 511) / 512;            // 782 <= 1024

    hipMemsetAsync(p.rowptr, 0, zbytes, stream);
    k_deg_hist<<<1024, 256, 0, stream>>>(p);
    k_scan1<<<nscan, 512, 0, stream>>>(p.rowptr, M, p.bsums);
    k_scan_top<<<1, 1024, 0, stream>>>(p.bsums, nscan, p.meta, p.out, out_size);
    k_scan_add<<<(M + 255) / 256, 256, 0, stream>>>(p.rowptr, p.cursor, M, 2 * E, p.bsums);
    k_fill<<<1024, 256, 0, stream>>>(p);

    void* args[] = { &p };
    hipLaunchCooperativeKernel((void*)k_sweep_f, dim3(G), dim3(256), args, 0, stream);
    hipLaunchCooperativeKernel((void*)k_sweep_b, dim3(G), dim3(256), args, 0, stream);
}

// Round 9
// 658.047 us; speedup vs baseline: 1.4131x; 1.4131x over previous
//
#include <hip/hip_runtime.h>
#include <float.h>

#define NLVL 12
#define NB   16

// meta: [0..16) cf | [16..32) cb | [32..48) co | [48..64) curf | [64..80) curb |
//       [80..96) curo | [96..109) base_f | [128..141) base_b | [160..177) base_o
// packed entry: id(18b) | fl(4b)<<18 | bl(4b)<<22 | tidx(4b)<<26   (N=200k < 2^18)
// tidx = nt*3+ninv in 0..8 -> h_init row = tab[tidx]  (h_init never materialized)

struct Params {
    const int *nt, *ninv, *src, *dst, *fl, *bl, *batch;
    const float *We, *be, *Wf, *bf, *Wb, *bb;
    float *hN, *hB, *out;
    int *rowptr, *cursor, *col, *nb_f, *nb_b, *onodes, *bsums, *meta, *plarr;
    int N, E, M, outN;
};

// ---------------- degrees + histograms + packed (fl,bl,tidx) ----------------
__global__ void k_deg_hist(Params p) {
    __shared__ int hf[NLVL], hb[NLVL], ho[NB];
    if (threadIdx.x < NLVL) { hf[threadIdx.x] = 0; hb[threadIdx.x] = 0; }
    if (threadIdx.x < NB) ho[threadIdx.x] = 0;
    __syncthreads();
    int g = blockIdx.x * blockDim.x + threadIdx.x, gs = gridDim.x * blockDim.x;
    for (int e = g; e < p.E; e += gs) {
        atomicAdd(&p.rowptr[p.dst[e]], 1);
        atomicAdd(&p.rowptr[p.N + p.src[e]], 1);
    }
    for (int i = g; i < p.N; i += gs) {
        int f = p.fl[i], b = p.bl[i];
        int t = p.nt[i], iv = p.ninv[i];
        p.plarr[i] = f | (b << 4) | ((t * 3 + iv) << 8);
        atomicAdd(&hf[f], 1);
        atomicAdd(&hb[b], 1);
        if (t == 1) atomicAdd(&ho[p.batch[i]], 1);
    }
    __syncthreads();
    if (threadIdx.x < NLVL) { atomicAdd(&p.meta[threadIdx.x], hf[threadIdx.x]); atomicAdd(&p.meta[16 + threadIdx.x], hb[threadIdx.x]); }
    if (threadIdx.x < NB) atomicAdd(&p.meta[32 + threadIdx.x], ho[threadIdx.x]);
}

// ---------------- 3-kernel exclusive scan over M = 2N ----------------
__global__ void k_scan1(int* __restrict__ data, int M, int* __restrict__ bsums) {
    __shared__ int s[512];
    int t = threadIdx.x;
    int g = blockIdx.x * 512 + t;
    int v = (g < M) ? data[g] : 0;
    s[t] = v;
    __syncthreads();
    for (int off = 1; off < 512; off <<= 1) {
        int add = (t >= off) ? s[t - off] : 0;
        __syncthreads();
        s[t] += add;
        __syncthreads();
    }
    if (g < M) data[g] = s[t] - v;
    if (t == 511) bsums[blockIdx.x] = s[511];
}

__global__ void k_scan_top(int* __restrict__ bsums, int nblk, int* __restrict__ meta,
                           float* __restrict__ out, int outN) {
    __shared__ int s[1024];
    int t = threadIdx.x;
    if (t == 0) { int a = 0; for (int l = 0; l < NLVL; l++) { meta[96 + l] = a; meta[48 + l] = a; a += meta[l]; } meta[96 + NLVL] = a; }
    if (t == 1) { int a = 0; for (int l = 0; l < NLVL; l++) { meta[128 + l] = a; meta[64 + l] = a; a += meta[16 + l]; } meta[128 + NLVL] = a; }
    if (t == 2) { int a = 0; for (int b = 0; b < NB; b++) { meta[160 + b] = a; meta[80 + b] = a; a += meta[32 + b]; } meta[160 + NB] = a; }
    for (int i = t; i < outN; i += 1024)
        out[i] = ((i & 127) < 64) ? -FLT_MAX : 0.0f;   // max-pool init == finfo.min
    int v = (t < nblk) ? bsums[t] : 0;
    s[t] = v;
    __syncthreads();
    for (int off = 1; off < 1024; off <<= 1) {
        int add = (t >= off) ? s[t - off] : 0;
        __syncthreads();
        s[t] += add;
        __syncthreads();
    }
    if (t < nblk) bsums[t] = s[t] - v;
}

__global__ void k_scan_add(int* __restrict__ rowptr, int* __restrict__ cursor, int M, int total,
                           const int* __restrict__ bsums) {
    int g = blockIdx.x * blockDim.x + threadIdx.x;
    if (g >= M) return;
    int r = rowptr[g] + bsums[g >> 9];
    rowptr[g] = r;
    cursor[g] = r;
    if (g == 0) rowptr[M] = total;
}

// ---------------- packed CSR fill + packed node scatter ----------------
__global__ void k_fill(Params p) {
    __shared__ int hf[NLVL], hb[NLVL], ho[NB], basef[NLVL], baseb[NLVL], baseo[NB];
    int g = blockIdx.x * blockDim.x + threadIdx.x, gs = gridDim.x * blockDim.x;
    int tid = threadIdx.x;
    int N = p.N;

    for (int e = g; e < p.E; e += gs) {
        int s = p.src[e], d = p.dst[e];
        p.col[atomicAdd(&p.cursor[d], 1)] = s | (p.plarr[s] << 18);      // in-edge: other = src
        p.col[atomicAdd(&p.cursor[N + s], 1)] = d | (p.plarr[d] << 18);  // out-edge: other = dst
    }

    for (int i0 = blockIdx.x * blockDim.x; i0 < N; i0 += gs) {
        int i = i0 + tid;
        bool valid = (i < N);
        if (tid < NLVL) { hf[tid] = 0; hb[tid] = 0; }
        if (tid < NB) ho[tid] = 0;
        __syncthreads();
        int lf = 0, lb = 0, ob = -1, pl = 0;
        if (valid) {
            pl = p.plarr[i];
            lf = pl & 15; lb = (pl >> 4) & 15;
            atomicAdd(&hf[lf], 1);
            atomicAdd(&hb[lb], 1);
            if (p.nt[i] == 1) { ob = p.batch[i]; atomicAdd(&ho[ob], 1); }
        }
        __syncthreads();
        if (tid < NLVL) {
            basef[tid] = atomicAdd(&p.meta[48 + tid], hf[tid]);
            baseb[tid] = atomicAdd(&p.meta[64 + tid], hb[tid]);
            hf[tid] = 0; hb[tid] = 0;
        }
        if (tid < NB) {
            baseo[tid] = atomicAdd(&p.meta[80 + tid], ho[tid]);
            ho[tid] = 0;
        }
        __syncthreads();
        if (valid) {
            int pk = i | (pl << 18);
            p.nb_f[basef[lf] + atomicAdd(&hf[lf], 1)] = pk;
            p.nb_b[baseb[lb] + atomicAdd(&hb[lb], 1)] = pk;
            if (ob >= 0) p.onodes[baseo[ob] + atomicAdd(&ho[ob], 1)] = pk;
        }
        __syncthreads();
    }
}

// ---------------- per-level sweep: gather + reg-resident matvec -------------
// 3-buffer rule (r6-verified logic): fwd writes hN always, bwd writes hB always.
//   fwd read : 0<flu<l -> hN[u], else tab[tidx]
//   bwd read : 0<blu<l -> hB[u], elif flu>0 -> hN[u], else tab[tidx]
__global__ __launch_bounds__(256) void k_sweep(Params p, int lvl, int dir) {
    __shared__ float tab[9 * 64];                       // 9 possible h_init rows
    const int tid = threadIdx.x, lane = tid & 63;
    for (int t = tid >> 6; t < 9; t += 4) {
        float nf = (float)(t / 3), iv = (float)(t % 3);
        tab[t * 64 + lane] = fmaf(nf, p.We[lane], fmaf(iv, p.We[64 + lane], p.be[lane]));
    }
    const float* W = dir ? p.Wb : p.Wf;
    float w[64];                                        // column `lane` of W in VGPRs
    #pragma unroll
    for (int k = 0; k < 64; k++) w[k] = W[k * 64 + lane];
    float bv = (dir ? p.bb : p.bf)[lane];
    __syncthreads();

    const int* nb = dir ? p.nb_b : p.nb_f;
    const int* rp = p.rowptr + (dir ? p.N : 0);
    int start = p.meta[(dir ? 128 : 96) + lvl];
    int cnt   = p.meta[(dir ? 128 : 96) + lvl + 1] - start;
    const int wid = (blockIdx.x * 256 + tid) >> 6;
    const int nw  = (gridDim.x * 256) >> 6;
    const int q = lane >> 4, fb = (lane & 15) * 4;
    float* db = dir ? p.hB : p.hN;

    int c0 = (int)((long long)cnt * wid / nw);
    int c1 = (int)((long long)cnt * (wid + 1) / nw);
    for (int g0 = c0; g0 < c1; g0 += 64) {
        int take = c1 - g0; if (take > 64) take = 64;
        int el = 0, rpvl = 0, rpel = 0;
        if (lane < take) {
            int e = nb[start + g0 + lane];              // coalesced id preload
            el = e;
            int v = e & 0x3FFFF;
            rpvl = rp[v]; rpel = rp[v + 1];
        }
        for (int j = 0; j < take; j++) {
            int e   = __shfl(el, j, 64);
            int rpv = __shfl(rpvl, j, 64);
            int rpe = __shfl(rpel, j, 64);
            int v   = e & 0x3FFFF;
            float4 acc = make_float4(0.f, 0.f, 0.f, 0.f);
            for (int cb = rpv + q; cb < rpe; cb += 4) {
                int cu = p.col[cb];                     // broadcast within quarter-wave
                int u = cu & 0x3FFFF;
                int flu = (cu >> 18) & 15, blu = (cu >> 22) & 15;
                const float* sp;
                if (dir == 0)
                    sp = (flu > 0 && flu < lvl) ? (p.hN + (size_t)u * 64)
                                                : (tab + ((cu >> 26) & 15) * 64);
                else
                    sp = (blu > 0 && blu < lvl) ? (p.hB + (size_t)u * 64)
                       : (flu > 0)              ? (p.hN + (size_t)u * 64)
                                                : (tab + ((cu >> 26) & 15) * 64);
                const float4 x = *(const float4*)(sp + fb);
                acc.x += x.x; acc.y += x.y; acc.z += x.z; acc.w += x.w;
            }
            acc.x += __shfl_xor(acc.x, 16, 64); acc.y += __shfl_xor(acc.y, 16, 64);
            acc.z += __shfl_xor(acc.z, 16, 64); acc.w += __shfl_xor(acc.w, 16, 64);
            acc.x += __shfl_xor(acc.x, 32, 64); acc.y += __shfl_xor(acc.y, 32, 64);
            acc.z += __shfl_xor(acc.z, 32, 64); acc.w += __shfl_xor(acc.w, 32, 64);
            float o = bv * (float)(rpe - rpv);
            #pragma unroll
            for (int m = 0; m < 16; m++) {              // a[4m+c] lives in lane m
                float ax = __shfl(acc.x, m, 64);
                float ay = __shfl(acc.y, m, 64);
                float az = __shfl(acc.z, m, 64);
                float aw = __shfl(acc.w, m, 64);
                o = fmaf(ax, w[4 * m + 0], o);
                o = fmaf(ay, w[4 * m + 1], o);
                o = fmaf(az, w[4 * m + 2], o);
                o = fmaf(aw, w[4 * m + 3], o);
            }
            db[(size_t)v * 64 + lane] = o;
        }
    }
}

// ---------------- readout ----------------
__device__ inline void atomicMaxF(float* addr, float val) {
    int* ai = (int*)addr;
    int old = *ai;
    while (__int_as_float(old) < val) {
        int assumed = old;
        old = atomicCAS(ai, assumed, __float_as_int(val));
        if (old == assumed) break;
    }
}

__global__ void k_readout(Params p) {
    __shared__ float tab[9 * 64];
    int lane = threadIdx.x & 63;
    for (int t = threadIdx.x >> 6; t < 9; t += 4) {
        float nf = (float)(t / 3), iv = (float)(t % 3);
        tab[t * 64 + lane] = fmaf(nf, p.We[lane], fmaf(iv, p.We[64 + lane], p.be[lane]));
    }
    __syncthreads();
    int b = blockIdx.x >> 5;          // batch
    int sl = blockIdx.x & 31;         // slice
    int a0 = p.meta[160 + b], a1 = p.meta[161 + b];
    int cnt = a1 - a0;
    if (cnt == 0) return;
    int lo = a0 + (int)((long long)cnt * sl / 32);
    int hi = a0 + (int)((long long)cnt * (sl + 1) / 32);
    int wcnt = hi - lo;
    int wave = threadIdx.x >> 6;
    int wl = lo + (wcnt * wave) / 4;
    int wh = lo + (wcnt * (wave + 1)) / 4;
    if (wh <= wl) return;
    float mx = -FLT_MAX, sm = 0.f;
    for (int k = wl; k < wh; k += 64) {
        int take = wh - k; if (take > 64) take = 64;
        int el = (lane < take) ? p.onodes[k + lane] : 0;
        for (int j = 0; j < take; j++) {
            int e = __shfl(el, j, 64);
            int v = e & 0x3FFFF;
            int flv = (e >> 18) & 15, blv = (e >> 22) & 15;
            const float* sp = (blv > 0) ? (p.hB + (size_t)v * 64)
                            : (flv > 0) ? (p.hN + (size_t)v * 64)
                                        : (tab + ((e >> 26) & 15) * 64);
            float x = sp[lane];
            mx = fmaxf(mx, x);
            sm += x;
        }
    }
    atomicMaxF(&p.out[b * 128 + lane], mx);
    atomicAdd(&p.out[b * 128 + 64 + lane], sm);
}

extern "C" void kernel_launch(void* const* d_in, const int* in_sizes, int n_in,
                              void* d_out, int out_size, void* d_ws, size_t ws_size,
                              hipStream_t stream) {
    int N = in_sizes[0];
    int E = in_sizes[2] / 2;
    int M = 2 * N;

    Params p;
    p.nt    = (const int*)d_in[0];
    p.ninv  = (const int*)d_in[1];
    p.src   = (const int*)d_in[2];
    p.dst   = (const int*)d_in[2] + E;
    p.fl    = (const int*)d_in[3];
    p.bl    = (const int*)d_in[4];
    p.batch = (const int*)d_in[5];
    p.We    = (const float*)d_in[6];
    p.be    = (const float*)d_in[7];
    p.Wf    = (const float*)d_in[8];
    p.bf    = (const float*)d_in[9];
    p.Wb    = (const float*)d_in[10];
    p.bb    = (const float*)d_in[11];
    p.out   = (float*)d_out;
    p.N = N; p.E = E; p.M = M; p.outN = out_size;

    char* ws = (char*)d_ws;
    size_t off = 0;
    auto alloc = [&](size_t bytes) -> char* {
        char* q = ws + off;
        off = (off + bytes + 255) & ~(size_t)255;
        return q;
    };
    // rowptr + meta adjacent -> one memset zeroes both
    p.rowptr = (int*)  alloc((size_t)(M + 1) * sizeof(int));
    p.meta   = (int*)  alloc(256 * sizeof(int));
    size_t zbytes = (size_t)((char*)(p.meta + 256) - (char*)p.rowptr);
    p.hN     = (float*)alloc((size_t)N * 64 * sizeof(float));
    p.hB     = (float*)alloc((size_t)N * 64 * sizeof(float));
    p.cursor = (int*)  alloc((size_t)M * sizeof(int));
    p.col    = (int*)  alloc((size_t)2 * E * sizeof(int));
    p.nb_f   = (int*)  alloc((size_t)N * sizeof(int));
    p.nb_b   = (int*)  alloc((size_t)N * sizeof(int));
    p.onodes = (int*)  alloc((size_t)N * sizeof(int));
    p.plarr  = (int*)  alloc((size_t)N * sizeof(int));
    p.bsums  = (int*)  alloc(1024 * sizeof(int));

    int nscan = (M + 511) / 512;            // 782 <= 1024

    hipMemsetAsync(p.rowptr, 0, zbytes, stream);
    k_deg_hist<<<1024, 256, 0, stream>>>(p);
    k_scan1<<<nscan, 512, 0, stream>>>(p.rowptr, M, p.bsums);
    k_scan_top<<<1, 1024, 0, stream>>>(p.bsums, nscan, p.meta, p.out, out_size);
    k_scan_add<<<(M + 255) / 256, 256, 0, stream>>>(p.rowptr, p.cursor, M, 2 * E, p.bsums);
    k_fill<<<1024, 256, 0, stream>>>(p);

    for (int l = 1; l < NLVL; l++)
        k_sweep<<<1024, 256, 0, stream>>>(p, l, 0);
    for (int l = 1; l < NLVL; l++)
        k_sweep<<<1024, 256, 0, stream>>>(p, l, 1);

    k_readout<<<NB * 32, 256, 0, stream>>>(p);
}

// Round 10
// 485.604 us; speedup vs baseline: 1.9148x; 1.3551x over previous
//
#include <hip/hip_runtime.h>
#include <float.h>

#define NLVL 12
#define NB   16

// meta: [0..16) cf | [16..32) cb | [32..48) co | [48..64) curf | [64..80) curb |
//       [80..96) curo | [96..109) base_f | [128..141) base_b | [160..177) base_o
// packed entry: id(18b) | fl(4b)<<18 | bl(4b)<<22 | tidx(4b)<<26   (N=200k < 2^18)
// tidx = nt*3+ninv in 0..8 -> h_init row = tab_g[tidx]  (h_init never materialized)

struct Params {
    const int *nt, *ninv, *src, *dst, *fl, *bl, *batch;
    const float *We, *be, *Wf, *bf, *Wb, *bb;
    float *hN, *hB, *tabg, *out;
    int *rowptr, *cursor, *col, *nb_f, *nb_b, *onodes, *bsums, *meta, *plarr;
    int N, E, M, outN;
};

__device__ __forceinline__ float rlanef(float x, int l) {
    return __int_as_float(__builtin_amdgcn_readlane(__float_as_int(x), l));
}

// ---------------- degrees + histograms + packed (fl,bl,tidx) ----------------
__global__ void k_deg_hist(Params p) {
    __shared__ int hf[NLVL], hb[NLVL], ho[NB];
    if (threadIdx.x < NLVL) { hf[threadIdx.x] = 0; hb[threadIdx.x] = 0; }
    if (threadIdx.x < NB) ho[threadIdx.x] = 0;
    __syncthreads();
    int g = blockIdx.x * blockDim.x + threadIdx.x, gs = gridDim.x * blockDim.x;
    for (int e = g; e < p.E; e += gs) {
        atomicAdd(&p.rowptr[p.dst[e]], 1);
        atomicAdd(&p.rowptr[p.N + p.src[e]], 1);
    }
    for (int i = g; i < p.N; i += gs) {
        int f = p.fl[i], b = p.bl[i];
        int t = p.nt[i], iv = p.ninv[i];
        p.plarr[i] = f | (b << 4) | ((t * 3 + iv) << 8);
        atomicAdd(&hf[f], 1);
        atomicAdd(&hb[b], 1);
        if (t == 1) atomicAdd(&ho[p.batch[i]], 1);
    }
    __syncthreads();
    if (threadIdx.x < NLVL) { atomicAdd(&p.meta[threadIdx.x], hf[threadIdx.x]); atomicAdd(&p.meta[16 + threadIdx.x], hb[threadIdx.x]); }
    if (threadIdx.x < NB) atomicAdd(&p.meta[32 + threadIdx.x], ho[threadIdx.x]);
}

// ---------------- 3-kernel exclusive scan over M = 2N ----------------
__global__ void k_scan1(int* __restrict__ data, int M, int* __restrict__ bsums) {
    __shared__ int s[512];
    int t = threadIdx.x;
    int g = blockIdx.x * 512 + t;
    int v = (g < M) ? data[g] : 0;
    s[t] = v;
    __syncthreads();
    for (int off = 1; off < 512; off <<= 1) {
        int add = (t >= off) ? s[t - off] : 0;
        __syncthreads();
        s[t] += add;
        __syncthreads();
    }
    if (g < M) data[g] = s[t] - v;
    if (t == 511) bsums[blockIdx.x] = s[511];
}

__global__ void k_scan_top(int* __restrict__ bsums, int nblk, Params p,
                           float* __restrict__ out, int outN) {
    __shared__ int s[1024];
    int* meta = p.meta;
    int t = threadIdx.x;
    if (t == 0) { int a = 0; for (int l = 0; l < NLVL; l++) { meta[96 + l] = a; meta[48 + l] = a; a += meta[l]; } meta[96 + NLVL] = a; }
    if (t == 1) { int a = 0; for (int l = 0; l < NLVL; l++) { meta[128 + l] = a; meta[64 + l] = a; a += meta[16 + l]; } meta[128 + NLVL] = a; }
    if (t == 2) { int a = 0; for (int b = 0; b < NB; b++) { meta[160 + b] = a; meta[80 + b] = a; a += meta[32 + b]; } meta[160 + NB] = a; }
    for (int i = t; i < outN; i += 1024)
        out[i] = ((i & 127) < 64) ? -FLT_MAX : 0.0f;   // max-pool init == finfo.min
    // 9-row h_init table: tab_g[t] = (t/3)*We[0] + (t%3)*We[1] + be
    if (t < 576) {
        int row = t >> 6, j = t & 63;
        float nf = (float)(row / 3), iv = (float)(row % 3);
        p.tabg[t] = fmaf(nf, p.We[j], fmaf(iv, p.We[64 + j], p.be[j]));
    }
    int v = (t < nblk) ? bsums[t] : 0;
    s[t] = v;
    __syncthreads();
    for (int off = 1; off < 1024; off <<= 1) {
        int add = (t >= off) ? s[t - off] : 0;
        __syncthreads();
        s[t] += add;
        __syncthreads();
    }
    if (t < nblk) bsums[t] = s[t] - v;
}

__global__ void k_scan_add(int* __restrict__ rowptr, int* __restrict__ cursor, int M, int total,
                           const int* __restrict__ bsums) {
    int g = blockIdx.x * blockDim.x + threadIdx.x;
    if (g >= M) return;
    int r = rowptr[g] + bsums[g >> 9];
    rowptr[g] = r;
    cursor[g] = r;
    if (g == 0) rowptr[M] = total;
}

// ---------------- packed CSR fill + packed node scatter ----------------
__global__ void k_fill(Params p) {
    __shared__ int hf[NLVL], hb[NLVL], ho[NB], basef[NLVL], baseb[NLVL], baseo[NB];
    int g = blockIdx.x * blockDim.x + threadIdx.x, gs = gridDim.x * blockDim.x;
    int tid = threadIdx.x;
    int N = p.N;

    for (int e = g; e < p.E; e += gs) {
        int s = p.src[e], d = p.dst[e];
        p.col[atomicAdd(&p.cursor[d], 1)] = s | (p.plarr[s] << 18);      // in-edge: other = src
        p.col[atomicAdd(&p.cursor[N + s], 1)] = d | (p.plarr[d] << 18);  // out-edge: other = dst
    }

    for (int i0 = blockIdx.x * blockDim.x; i0 < N; i0 += gs) {
        int i = i0 + tid;
        bool valid = (i < N);
        if (tid < NLVL) { hf[tid] = 0; hb[tid] = 0; }
        if (tid < NB) ho[tid] = 0;
        __syncthreads();
        int lf = 0, lb = 0, ob = -1, pl = 0;
        if (valid) {
            pl = p.plarr[i];
            lf = pl & 15; lb = (pl >> 4) & 15;
            atomicAdd(&hf[lf], 1);
            atomicAdd(&hb[lb], 1);
            if (p.nt[i] == 1) { ob = p.batch[i]; atomicAdd(&ho[ob], 1); }
        }
        __syncthreads();
        if (tid < NLVL) {
            basef[tid] = atomicAdd(&p.meta[48 + tid], hf[tid]);
            baseb[tid] = atomicAdd(&p.meta[64 + tid], hb[tid]);
            hf[tid] = 0; hb[tid] = 0;
        }
        if (tid < NB) {
            baseo[tid] = atomicAdd(&p.meta[80 + tid], ho[tid]);
            ho[tid] = 0;
        }
        __syncthreads();
        if (valid) {
            int pk = i | (pl << 18);
            p.nb_f[basef[lf] + atomicAdd(&hf[lf], 1)] = pk;
            p.nb_b[baseb[lb] + atomicAdd(&hb[lb], 1)] = pk;
            if (ob >= 0) p.onodes[baseo[ob] + atomicAdd(&ho[ob], 1)] = pk;
        }
        __syncthreads();
    }
}

// ---------------- per-level sweep: quarter-per-node gather + VALU matvec ----
// (zero DS ops: no shfl, no LDS; broadcast via v_readlane -> SGPR operand)
// 3-buffer rule (verified r6/r9): fwd writes hN, bwd writes hB.
//   fwd read : 0<flu<l -> hN[u], else tab_g[tidx]
//   bwd read : 0<blu<l -> hB[u], elif flu>0 -> hN[u], else tab_g[tidx]
__global__ __launch_bounds__(256, 4) void k_sweep(Params p, int lvl, int dir) {
    const int tid = threadIdx.x, lane = tid & 63;
    const float* W = dir ? p.Wb : p.Wf;
    float w[64];                                        // column `lane` of W in VGPRs
    #pragma unroll
    for (int k = 0; k < 64; k++) w[k] = W[k * 64 + lane];
    float bv = (dir ? p.bb : p.bf)[lane];

    const int* nb = dir ? p.nb_b : p.nb_f;
    const int* rp = p.rowptr + (dir ? p.N : 0);
    int start = p.meta[(dir ? 128 : 96) + lvl];
    int cnt   = p.meta[(dir ? 128 : 96) + lvl + 1] - start;
    const int wid = (blockIdx.x * 256 + tid) >> 6;
    const int nw  = (gridDim.x * 256) >> 6;
    const int q = lane >> 4, fb = (lane & 15) * 4;
    float* db = dir ? p.hB : p.hN;

    int c0 = (int)((long long)cnt * wid / nw);
    int c1 = (int)((long long)cnt * (wid + 1) / nw);
    for (int i = c0; i < c1; i += 4) {
        int my = i + q;                                 // quarter q owns node `my`
        int v = 0, rpv = 0, rpe = 0;
        if (my < c1) {
            int e = nb[start + my];                     // broadcast within quarter
            v = e & 0x3FFFF;
            rpv = rp[v]; rpe = rp[v + 1];
        }
        float4 acc = make_float4(0.f, 0.f, 0.f, 0.f);
        for (int cb = rpv; cb < rpe; cb++) {            // ALL neighbors of own node
            int cu = p.col[cb];                         // broadcast within quarter
            int u = cu & 0x3FFFF;
            int flu = (cu >> 18) & 15, blu = (cu >> 22) & 15;
            const float* sp;
            if (dir == 0)
                sp = (flu > 0 && flu < lvl) ? (p.hN + (size_t)u * 64)
                                            : (p.tabg + ((cu >> 26) & 15) * 64);
            else
                sp = (blu > 0 && blu < lvl) ? (p.hB + (size_t)u * 64)
                   : (flu > 0)              ? (p.hN + (size_t)u * 64)
                                            : (p.tabg + ((cu >> 26) & 15) * 64);
            const float4 x = *(const float4*)(sp + fb); // 16 lanes cover the row
            acc.x += x.x; acc.y += x.y; acc.z += x.z; acc.w += x.w;
        }
        // matvec per node, a-broadcast via readlane (VALU/SALU only)
        #pragma unroll
        for (int qq = 0; qq < 4; qq++) {
            if (i + qq >= c1) break;                    // wave-uniform
            int vs   = __builtin_amdgcn_readlane(v, 16 * qq);
            int degs = __builtin_amdgcn_readlane(rpe, 16 * qq)
                     - __builtin_amdgcn_readlane(rpv, 16 * qq);
            float o = bv * (float)degs;
            #pragma unroll
            for (int m = 0; m < 16; m++) {
                float ax = rlanef(acc.x, 16 * qq + m);
                float ay = rlanef(acc.y, 16 * qq + m);
                float az = rlanef(acc.z, 16 * qq + m);
                float aw = rlanef(acc.w, 16 * qq + m);
                o = fmaf(ax, w[4 * m + 0], o);
                o = fmaf(ay, w[4 * m + 1], o);
                o = fmaf(az, w[4 * m + 2], o);
                o = fmaf(aw, w[4 * m + 3], o);
            }
            db[(size_t)vs * 64 + lane] = o;             // coalesced 256B store
        }
    }
}

// ---------------- readout ----------------
__device__ inline void atomicMaxF(float* addr, float val) {
    int* ai = (int*)addr;
    int old = *ai;
    while (__int_as_float(old) < val) {
        int assumed = old;
        old = atomicCAS(ai, assumed, __float_as_int(val));
        if (old == assumed) break;
    }
}

__global__ void k_readout(Params p) {
    int lane = threadIdx.x & 63;
    int b = blockIdx.x >> 5;          // batch
    int sl = blockIdx.x & 31;         // slice
    int a0 = p.meta[160 + b], a1 = p.meta[161 + b];
    int cnt = a1 - a0;
    if (cnt == 0) return;
    int lo = a0 + (int)((long long)cnt * sl / 32);
    int hi = a0 + (int)((long long)cnt * (sl + 1) / 32);
    int wcnt = hi - lo;
    int wave = threadIdx.x >> 6;
    int wl = lo + (wcnt * wave) / 4;
    int wh = lo + (wcnt * (wave + 1)) / 4;
    if (wh <= wl) return;
    float mx = -FLT_MAX, sm = 0.f;
    for (int k = wl; k < wh; k += 64) {
        int take = wh - k; if (take > 64) take = 64;
        int el = (lane < take) ? p.onodes[k + lane] : 0;
        for (int j = 0; j < take; j++) {
            int e = __shfl(el, j, 64);
            int v = e & 0x3FFFF;
            int flv = (e >> 18) & 15, blv = (e >> 22) & 15;
            const float* sp = (blv > 0) ? (p.hB + (size_t)v * 64)
                            : (flv > 0) ? (p.hN + (size_t)v * 64)
                                        : (p.tabg + ((e >> 26) & 15) * 64);
            float x = sp[lane];
            mx = fmaxf(mx, x);
            sm += x;
        }
    }
    atomicMaxF(&p.out[b * 128 + lane], mx);
    atomicAdd(&p.out[b * 128 + 64 + lane], sm);
}

extern "C" void kernel_launch(void* const* d_in, const int* in_sizes, int n_in,
                              void* d_out, int out_size, void* d_ws, size_t ws_size,
                              hipStream_t stream) {
    int N = in_sizes[0];
    int E = in_sizes[2] / 2;
    int M = 2 * N;

    Params p;
    p.nt    = (const int*)d_in[0];
    p.ninv  = (const int*)d_in[1];
    p.src   = (const int*)d_in[2];
    p.dst   = (const int*)d_in[2] + E;
    p.fl    = (const int*)d_in[3];
    p.bl    = (const int*)d_in[4];
    p.batch = (const int*)d_in[5];
    p.We    = (const float*)d_in[6];
    p.be    = (const float*)d_in[7];
    p.Wf    = (const float*)d_in[8];
    p.bf    = (const float*)d_in[9];
    p.Wb    = (const float*)d_in[10];
    p.bb    = (const float*)d_in[11];
    p.out   = (float*)d_out;
    p.N = N; p.E = E; p.M = M; p.outN = out_size;

    char* ws = (char*)d_ws;
    size_t off = 0;
    auto alloc = [&](size_t bytes) -> char* {
        char* q = ws + off;
        off = (off + bytes + 255) & ~(size_t)255;
        return q;
    };
    // rowptr + meta adjacent -> one memset zeroes both
    p.rowptr = (int*)  alloc((size_t)(M + 1) * sizeof(int));
    p.meta   = (int*)  alloc(256 * sizeof(int));
    size_t zbytes = (size_t)((char*)(p.meta + 256) - (char*)p.rowptr);
    p.hN     = (float*)alloc((size_t)N * 64 * sizeof(float));
    p.hB     = (float*)alloc((size_t)N * 64 * sizeof(float));
    p.tabg   = (float*)alloc(9 * 64 * sizeof(float));
    p.cursor = (int*)  alloc((size_t)M * sizeof(int));
    p.col    = (int*)  alloc((size_t)2 * E * sizeof(int));
    p.nb_f   = (int*)  alloc((size_t)N * sizeof(int));
    p.nb_b   = (int*)  alloc((size_t)N * sizeof(int));
    p.onodes = (int*)  alloc((size_t)N * sizeof(int));
    p.plarr  = (int*)  alloc((size_t)N * sizeof(int));
    p.bsums  = (int*)  alloc(1024 * sizeof(int));

    int nscan = (M + 511) / 512;            // 782 <= 1024

    hipMemsetAsync(p.rowptr, 0, zbytes, stream);
    k_deg_hist<<<1024, 256, 0, stream>>>(p);
    k_scan1<<<nscan, 512, 0, stream>>>(p.rowptr, M, p.bsums);
    k_scan_top<<<1, 1024, 0, stream>>>(p.bsums, nscan, p, p.out, out_size);
    k_scan_add<<<(M + 255) / 256, 256, 0, stream>>>(p.rowptr, p.cursor, M, 2 * E, p.bsums);
    k_fill<<<1024, 256, 0, stream>>>(p);

    for (int l = 1; l < NLVL; l++)
        k_sweep<<<1024, 256, 0, stream>>>(p, l, 0);
    for (int l = 1; l < NLVL; l++)
        k_sweep<<<1024, 256, 0, stream>>>(p, l, 1);

    k_readout<<<NB * 32, 256, 0, stream>>>(p);
}

// Round 11
// 477.844 us; speedup vs baseline: 1.9459x; 1.0162x over previous
//
#include <hip/hip_runtime.h>
#include <float.h>

#define NLVL 12
#define NB   16
#define NBLK 256    // blocks for deg_hist / fill (per-block count arrays sized to this)

// meta: [96..109) base_f | [128..141) base_b | [160..177) base_o
// packed entry: id(18b) | fl(4b)<<18 | bl(4b)<<22 | tidx(4b)<<26   (N=200k < 2^18)
// tidx = nt*3+ninv in 0..8 -> h_init row = tabg[tidx]  (h_init never materialized)

struct Params {
    const int *nt, *ninv, *src, *dst, *fl, *bl, *batch;
    const float *We, *be, *Wf, *bf, *Wb, *bb;
    float *hN, *hB, *tabg, *out;
    int *rowptr, *cursor, *col, *nb_f, *nb_b, *onodes, *bsums, *meta, *plarr;
    int *cntf, *cntb, *cnto, *blkf, *blkb, *blko;
    int N, E, M, outN;
};

__device__ __forceinline__ float rlanef(float x, int l) {
    return __int_as_float(__builtin_amdgcn_readlane(__float_as_int(x), l));
}

// ---------------- degrees + per-block histograms + packed (fl,bl,tidx) -------
__global__ void k_deg_hist(Params p) {
    __shared__ int hf[NLVL], hb[NLVL], ho[NB];
    int tid = threadIdx.x, bid = blockIdx.x;
    if (tid < NLVL) { hf[tid] = 0; hb[tid] = 0; }
    if (tid < NB) ho[tid] = 0;
    __syncthreads();
    int g = bid * 256 + tid, gs = gridDim.x * 256;
    for (int e = g; e < p.E; e += gs) {               // fire-and-forget atomics
        atomicAdd(&p.rowptr[p.dst[e]], 1);
        atomicAdd(&p.rowptr[p.N + p.src[e]], 1);
    }
    // chunk-owned nodes (same chunk map as k_fill!)
    int chunk = (p.N + gridDim.x - 1) / gridDim.x;
    int lo = bid * chunk, hi = lo + chunk; if (hi > p.N) hi = p.N;
    for (int i = lo + tid; i < hi; i += 256) {
        int f = p.fl[i], b = p.bl[i];
        int t = p.nt[i], iv = p.ninv[i];
        p.plarr[i] = f | (b << 4) | ((t * 3 + iv) << 8);
        atomicAdd(&hf[f], 1);
        atomicAdd(&hb[b], 1);
        if (t == 1) atomicAdd(&ho[p.batch[i]], 1);
    }
    __syncthreads();
    if (tid < NLVL) { p.cntf[tid * NBLK + bid] = hf[tid]; p.cntb[tid * NBLK + bid] = hb[tid]; }
    if (tid < NB) p.cnto[tid * NBLK + bid] = ho[tid];
}

// ---------------- 3-kernel exclusive scan over M = 2N ----------------
__global__ void k_scan1(int* __restrict__ data, int M, int* __restrict__ bsums) {
    __shared__ int s[512];
    int t = threadIdx.x;
    int g = blockIdx.x * 512 + t;
    int v = (g < M) ? data[g] : 0;
    s[t] = v;
    __syncthreads();
    for (int off = 1; off < 512; off <<= 1) {
        int add = (t >= off) ? s[t - off] : 0;
        __syncthreads();
        s[t] += add;
        __syncthreads();
    }
    if (g < M) data[g] = s[t] - v;
    if (t == 511) bsums[blockIdx.x] = s[511];
}

// scan_top: bsums scan + per-block-base segmented scans + meta bases + tabg + out init
__global__ void k_scan_top(int* __restrict__ bsums, int nblk, Params p,
                           float* __restrict__ out, int outN) {
    __shared__ int s[1024];
    __shared__ int tot[48];     // fwd [0..12), bwd [16..28), out [32..48)
    int t = threadIdx.x;
    int* meta = p.meta;
    for (int i = t; i < outN; i += 1024)
        out[i] = ((i & 127) < 64) ? -FLT_MAX : 0.0f;   // max-pool init == finfo.min
    if (t < 576) {              // 9-row h_init table
        int row = t >> 6, j = t & 63;
        float nf = (float)(row / 3), iv = (float)(row % 3);
        p.tabg[t] = fmaf(nf, p.We[j], fmaf(iv, p.We[64 + j], p.be[j]));
    }
    // segmented scans: 4 segments of NBLK=256 per round
    int seg = t >> 8, b = t & 255;
    for (int r = 0; r < 3; r++) {                      // fwd levels 4r+seg
        int l = 4 * r + seg;
        int v = p.cntf[l * NBLK + b];
        s[t] = v; __syncthreads();
        for (int off = 1; off < NBLK; off <<= 1) {
            int add = (b >= off) ? s[t - off] : 0; __syncthreads();
            s[t] += add; __syncthreads();
        }
        p.blkf[l * NBLK + b] = s[t] - v;
        if (b == NBLK - 1) tot[l] = s[t];
        __syncthreads();
    }
    for (int r = 0; r < 3; r++) {                      // bwd levels
        int l = 4 * r + seg;
        int v = p.cntb[l * NBLK + b];
        s[t] = v; __syncthreads();
        for (int off = 1; off < NBLK; off <<= 1) {
            int add = (b >= off) ? s[t - off] : 0; __syncthreads();
            s[t] += add; __syncthreads();
        }
        p.blkb[l * NBLK + b] = s[t] - v;
        if (b == NBLK - 1) tot[16 + l] = s[t];
        __syncthreads();
    }
    for (int r = 0; r < 4; r++) {                      // output-node batches
        int l = 4 * r + seg;
        int v = p.cnto[l * NBLK + b];
        s[t] = v; __syncthreads();
        for (int off = 1; off < NBLK; off <<= 1) {
            int add = (b >= off) ? s[t - off] : 0; __syncthreads();
            s[t] += add; __syncthreads();
        }
        p.blko[l * NBLK + b] = s[t] - v;
        if (b == NBLK - 1) tot[32 + l] = s[t];
        __syncthreads();
    }
    if (t == 0) { int a = 0; for (int l = 0; l < NLVL; l++) { meta[96 + l] = a; a += tot[l]; } meta[96 + NLVL] = a; }
    if (t == 1) { int a = 0; for (int l = 0; l < NLVL; l++) { meta[128 + l] = a; a += tot[16 + l]; } meta[128 + NLVL] = a; }
    if (t == 2) { int a = 0; for (int l = 0; l < NB; l++) { meta[160 + l] = a; a += tot[32 + l]; } meta[160 + NB] = a; }
    __syncthreads();
    for (int i = t; i < NLVL * NBLK; i += 1024) p.blkf[i] += meta[96 + (i >> 8)];
    for (int i = t; i < NLVL * NBLK; i += 1024) p.blkb[i] += meta[128 + (i >> 8)];
    for (int i = t; i < NB * NBLK; i += 1024) p.blko[i] += meta[160 + (i >> 8)];
    // bsums scan (rowptr block offsets)
    int v = (t < nblk) ? bsums[t] : 0;
    s[t] = v;
    __syncthreads();
    for (int off = 1; off < 1024; off <<= 1) {
        int add = (t >= off) ? s[t - off] : 0;
        __syncthreads();
        s[t] += add;
        __syncthreads();
    }
    if (t < nblk) bsums[t] = s[t] - v;
}

__global__ void k_scan_add(int* __restrict__ rowptr, int* __restrict__ cursor, int M, int total,
                           const int* __restrict__ bsums) {
    int g = blockIdx.x * blockDim.x + threadIdx.x;
    if (g >= M) return;
    int r = rowptr[g] + bsums[g >> 9];
    rowptr[g] = r;
    cursor[g] = r;
    if (g == 0) rowptr[M] = total;
}

// ---------------- packed CSR fill + node scatter (LDS cursors, no global reservation) ----
__global__ void k_fill(Params p) {
    __shared__ int cur[48];     // fwd [0..12), bwd [16..28), out [32..48)
    int tid = threadIdx.x, bid = blockIdx.x;
    int g = bid * 256 + tid, gs = gridDim.x * 256;
    int N = p.N;

    // edge scatter (per-node cursor atomics: 196k distinct addresses, low contention)
    for (int e = g; e < p.E; e += gs) {
        int s = p.src[e], d = p.dst[e];
        p.col[atomicAdd(&p.cursor[d], 1)] = s | (p.plarr[s] << 18);      // in-edge: other = src
        p.col[atomicAdd(&p.cursor[N + s], 1)] = d | (p.plarr[d] << 18);  // out-edge: other = dst
    }

    // node scatter from precomputed per-block bases
    if (tid < NLVL) { cur[tid] = p.blkf[tid * NBLK + bid]; cur[16 + tid] = p.blkb[tid * NBLK + bid]; }
    if (tid < NB) cur[32 + tid] = p.blko[tid * NBLK + bid];
    __syncthreads();
    int chunk = (N + gridDim.x - 1) / gridDim.x;
    int lo = bid * chunk, hi = lo + chunk; if (hi > N) hi = N;
    for (int i = lo + tid; i < hi; i += 256) {
        int pl = p.plarr[i];
        int lf = pl & 15, lb = (pl >> 4) & 15, tx = (pl >> 8) & 15;
        int pk = i | (pl << 18);
        p.nb_f[atomicAdd(&cur[lf], 1)] = pk;
        p.nb_b[atomicAdd(&cur[16 + lb], 1)] = pk;
        if (tx >= 3 && tx < 6)                          // nt == 1
            p.onodes[atomicAdd(&cur[32 + p.batch[i]], 1)] = pk;
    }
}

// ---------------- per-level sweep: quarter-per-node gather + VALU matvec ----
// (zero DS ops; broadcast via v_readlane — champion r10 code, unchanged)
__global__ __launch_bounds__(256, 4) void k_sweep(Params p, int lvl, int dir) {
    const int tid = threadIdx.x, lane = tid & 63;
    const float* W = dir ? p.Wb : p.Wf;
    float w[64];
    #pragma unroll
    for (int k = 0; k < 64; k++) w[k] = W[k * 64 + lane];
    float bv = (dir ? p.bb : p.bf)[lane];

    const int* nb = dir ? p.nb_b : p.nb_f;
    const int* rp = p.rowptr + (dir ? p.N : 0);
    int start = p.meta[(dir ? 128 : 96) + lvl];
    int cnt   = p.meta[(dir ? 128 : 96) + lvl + 1] - start;
    const int wid = (blockIdx.x * 256 + tid) >> 6;
    const int nw  = (gridDim.x * 256) >> 6;
    const int q = lane >> 4, fb = (lane & 15) * 4;
    float* db = dir ? p.hB : p.hN;

    int c0 = (int)((long long)cnt * wid / nw);
    int c1 = (int)((long long)cnt * (wid + 1) / nw);
    for (int i = c0; i < c1; i += 4) {
        int my = i + q;
        int v = 0, rpv = 0, rpe = 0;
        if (my < c1) {
            int e = nb[start + my];
            v = e & 0x3FFFF;
            rpv = rp[v]; rpe = rp[v + 1];
        }
        float4 acc = make_float4(0.f, 0.f, 0.f, 0.f);
        for (int cb = rpv; cb < rpe; cb++) {
            int cu = p.col[cb];
            int u = cu & 0x3FFFF;
            int flu = (cu >> 18) & 15, blu = (cu >> 22) & 15;
            const float* sp;
            if (dir == 0)
                sp = (flu > 0 && flu < lvl) ? (p.hN + (size_t)u * 64)
                                            : (p.tabg + ((cu >> 26) & 15) * 64);
            else
                sp = (blu > 0 && blu < lvl) ? (p.hB + (size_t)u * 64)
                   : (flu > 0)              ? (p.hN + (size_t)u * 64)
                                            : (p.tabg + ((cu >> 26) & 15) * 64);
            const float4 x = *(const float4*)(sp + fb);
            acc.x += x.x; acc.y += x.y; acc.z += x.z; acc.w += x.w;
        }
        #pragma unroll
        for (int qq = 0; qq < 4; qq++) {
            if (i + qq >= c1) break;                    // wave-uniform
            int vs   = __builtin_amdgcn_readlane(v, 16 * qq);
            int degs = __builtin_amdgcn_readlane(rpe, 16 * qq)
                     - __builtin_amdgcn_readlane(rpv, 16 * qq);
            float o = bv * (float)degs;
            #pragma unroll
            for (int m = 0; m < 16; m++) {
                float ax = rlanef(acc.x, 16 * qq + m);
                float ay = rlanef(acc.y, 16 * qq + m);
                float az = rlanef(acc.z, 16 * qq + m);
                float aw = rlanef(acc.w, 16 * qq + m);
                o = fmaf(ax, w[4 * m + 0], o);
                o = fmaf(ay, w[4 * m + 1], o);
                o = fmaf(az, w[4 * m + 2], o);
                o = fmaf(aw, w[4 * m + 3], o);
            }
            db[(size_t)vs * 64 + lane] = o;
        }
    }
}

// ---------------- readout ----------------
__device__ inline void atomicMaxF(float* addr, float val) {
    int* ai = (int*)addr;
    int old = *ai;
    while (__int_as_float(old) < val) {
        int assumed = old;
        old = atomicCAS(ai, assumed, __float_as_int(val));
        if (old == assumed) break;
    }
}

__global__ void k_readout(Params p) {
    int lane = threadIdx.x & 63;
    int b = blockIdx.x >> 5;
    int sl = blockIdx.x & 31;
    int a0 = p.meta[160 + b], a1 = p.meta[161 + b];
    int cnt = a1 - a0;
    if (cnt == 0) return;
    int lo = a0 + (int)((long long)cnt * sl / 32);
    int hi = a0 + (int)((long long)cnt * (sl + 1) / 32);
    int wcnt = hi - lo;
    int wave = threadIdx.x >> 6;
    int wl = lo + (wcnt * wave) / 4;
    int wh = lo + (wcnt * (wave + 1)) / 4;
    if (wh <= wl) return;
    float mx = -FLT_MAX, sm = 0.f;
    for (int k = wl; k < wh; k += 64) {
        int take = wh - k; if (take > 64) take = 64;
        int el = (lane < take) ? p.onodes[k + lane] : 0;
        for (int j = 0; j < take; j++) {
            int e = __shfl(el, j, 64);
            int v = e & 0x3FFFF;
            int flv = (e >> 18) & 15, blv = (e >> 22) & 15;
            const float* sp = (blv > 0) ? (p.hB + (size_t)v * 64)
                            : (flv > 0) ? (p.hN + (size_t)v * 64)
                                        : (p.tabg + ((e >> 26) & 15) * 64);
            float x = sp[lane];
            mx = fmaxf(mx, x);
            sm += x;
        }
    }
    atomicMaxF(&p.out[b * 128 + lane], mx);
    atomicAdd(&p.out[b * 128 + 64 + lane], sm);
}

extern "C" void kernel_launch(void* const* d_in, const int* in_sizes, int n_in,
                              void* d_out, int out_size, void* d_ws, size_t ws_size,
                              hipStream_t stream) {
    int N = in_sizes[0];
    int E = in_sizes[2] / 2;
    int M = 2 * N;

    Params p;
    p.nt    = (const int*)d_in[0];
    p.ninv  = (const int*)d_in[1];
    p.src   = (const int*)d_in[2];
    p.dst   = (const int*)d_in[2] + E;
    p.fl    = (const int*)d_in[3];
    p.bl    = (const int*)d_in[4];
    p.batch = (const int*)d_in[5];
    p.We    = (const float*)d_in[6];
    p.be    = (const float*)d_in[7];
    p.Wf    = (const float*)d_in[8];
    p.bf    = (const float*)d_in[9];
    p.Wb    = (const float*)d_in[10];
    p.bb    = (const float*)d_in[11];
    p.out   = (float*)d_out;
    p.N = N; p.E = E; p.M = M; p.outN = out_size;

    char* ws = (char*)d_ws;
    size_t off = 0;
    auto alloc = [&](size_t bytes) -> char* {
        char* q = ws + off;
        off = (off + bytes + 255) & ~(size_t)255;
        return q;
    };
    // rowptr + meta adjacent -> one memset zeroes both
    p.rowptr = (int*)  alloc((size_t)(M + 1) * sizeof(int));
    p.meta   = (int*)  alloc(256 * sizeof(int));
    size_t zbytes = (size_t)((char*)(p.meta + 256) - (char*)p.rowptr);
    p.hN     = (float*)alloc((size_t)N * 64 * sizeof(float));
    p.hB     = (float*)alloc((size_t)N * 64 * sizeof(float));
    p.tabg   = (float*)alloc(9 * 64 * sizeof(float));
    p.cursor = (int*)  alloc((size_t)M * sizeof(int));
    p.col    = (int*)  alloc((size_t)2 * E * sizeof(int));
    p.nb_f   = (int*)  alloc((size_t)N * sizeof(int));
    p.nb_b   = (int*)  alloc((size_t)N * sizeof(int));
    p.onodes = (int*)  alloc((size_t)N * sizeof(int));
    p.plarr  = (int*)  alloc((size_t)N * sizeof(int));
    p.bsums  = (int*)  alloc(1024 * sizeof(int));
    p.cntf   = (int*)  alloc(NLVL * NBLK * sizeof(int));
    p.cntb   = (int*)  alloc(NLVL * NBLK * sizeof(int));
    p.cnto   = (int*)  alloc(NB * NBLK * sizeof(int));
    p.blkf   = (int*)  alloc(NLVL * NBLK * sizeof(int));
    p.blkb   = (int*)  alloc(NLVL * NBLK * sizeof(int));
    p.blko   = (int*)  alloc(NB * NBLK * sizeof(int));

    int nscan = (M + 511) / 512;            // 782 <= 1024

    hipMemsetAsync(p.rowptr, 0, zbytes, stream);
    k_deg_hist<<<NBLK, 256, 0, stream>>>(p);
    k_scan1<<<nscan, 512, 0, stream>>>(p.rowptr, M, p.bsums);
    k_scan_top<<<1, 1024, 0, stream>>>(p.bsums, nscan, p, p.out, out_size);
    k_scan_add<<<(M + 255) / 256, 256, 0, stream>>>(p.rowptr, p.cursor, M, 2 * E, p.bsums);
    k_fill<<<NBLK, 256, 0, stream>>>(p);

    for (int l = 1; l < NLVL; l++)
        k_sweep<<<1024, 256, 0, stream>>>(p, l, 0);
    for (int l = 1; l < NLVL; l++)
        k_sweep<<<1024, 256, 0, stream>>>(p, l, 1);

    k_readout<<<NB * 32, 256, 0, stream>>>(p);
}